// Round 9
// baseline (29.269 us; speedup 1.0000x reference)
//
#include <hip/hip_runtime.h>
#include <stdint.h>

// Edgenet: 4-channel fixed 3x3 Sobel-family stencil on [64,1,512,512] f32,
// edge = (sum_c |conv_c|) > 0 ? 1 : 0, output int32 [64,512,512].
//
// Round-9: T3/T4-style continuous pipeline. Each block owns 32 rows of one
// image and walks 4 sub-tiles (8 output rows, 10 staged rows = 20 KB) with
// double-buffered LDS. Staging uses __builtin_amdgcn_global_load_lds (16B,
// no VGPR round-trip); the NEXT tile's loads are issued BEFORE the current
// tile's compute and stay in flight across a raw s_barrier with a counted
// s_waitcnt vmcnt(N) (never a full drain in the loop) -- both HBM streams
// (read + write) run continuously instead of phase-alternating. 1024 blocks
// = exactly 4 blocks/CU (40 KB LDS), single generation, no tail. Vertical
// tile walk makes each tile's top halo rows L2-hits from the previous tile.
// vmcnt ledger per iteration: stage(t+1)=5 gload_lds + stores(t-1)=4 ->
// wait vmcnt(9) guarantees stage(t) complete (5 at t=0, 4 at t=3).

#define IMG_W 512
#define IMG_H 512
#define TROWS 8              // output rows per sub-tile
#define SROWS 10             // staged rows per sub-tile (incl halo)
#define NTILES 4             // sub-tiles per block

struct Row {
  float4 lo, hi;   // pixels 8l..8l+3, 8l+4..8l+7
  float lft, rgt;  // halo pixels 8l-1, 8l+8
};

__device__ __forceinline__ float rget(const Row& r, int k) {
  switch (k) {   // k is compile-time constant after full unroll
    case 0: return r.lft;
    case 1: return r.lo.x; case 2: return r.lo.y;
    case 3: return r.lo.z; case 4: return r.lo.w;
    case 5: return r.hi.x; case 6: return r.hi.y;
    case 7: return r.hi.z; case 8: return r.hi.w;
    default: return r.rgt;
  }
}

__device__ __forceinline__ void compute_store(const Row& T, const Row& M,
                                              const Row& B, int* orow) {
  int res[8];
#pragma unroll
  for (int j = 0; j < 8; ++j) {
    float t0 = rget(T, j), t1 = rget(T, j + 1), t2 = rget(T, j + 2);
    float m0 = rget(M, j),                      m2 = rget(M, j + 2);
    float b0 = rget(B, j), b1 = rget(B, j + 1), b2 = rget(B, j + 2);
    float tx = (b0 - t0) + 2.f * (b1 - t1) + (b2 - t2);            // f_x
    float ty = (t2 - t0) + 2.f * (m2 - m0) + (b2 - b0);            // f_y
    float d1 = -2.f * t0 - t1 - m0 + m2 + b1 + 2.f * b2;           // f_tl_br
    float d2 = -t1 - 2.f * t2 + m0 - m2 + 2.f * b0 + b1;           // f_tr_bl
    float e = fabsf(tx) + fabsf(ty) + fabsf(d1) + fabsf(d2);
    res[j] = (e > 0.f) ? 1 : 0;
  }
  *reinterpret_cast<int4*>(orow)     = make_int4(res[0], res[1], res[2], res[3]);
  *reinterpret_cast<int4*>(orow + 4) = make_int4(res[4], res[5], res[6], res[7]);
}

// Stage SROWS rows (image rows y0-1 .. y0+8, row-clamped) into buf.
// 5 x 16B global_load_lds per thread; LDS dest linear (wave-uniform base +
// lane*16), global source per-lane with row clamp. 20 KB total per tile.
__device__ __forceinline__ void stage_tile(const char* img, int y0,
                                           float* buf, int w, int lane) {
#pragma unroll
  for (int k = 0; k < 5; ++k) {
    int Bo  = (k << 12) | (w << 10) | (lane << 4);      // byte 0..20464
    int row = min(max(y0 - 1 + (Bo >> 11), 0), IMG_H - 1);
    const char* g = img + ((size_t)row << 11) + (Bo & 2047);
    char* l = reinterpret_cast<char*>(buf) + ((k << 12) | (w << 10));
    __builtin_amdgcn_global_load_lds(
        (const __attribute__((address_space(1))) uint32_t*)g,
        (__attribute__((address_space(3))) uint32_t*)l, 16, 0, 0);
  }
}

__device__ __forceinline__ void ldrow(const float* buf, int lr, int imgrow,
                                      int lane, Row& r) {
  const float* p = buf + lr * IMG_W + (lane << 3);
  float4 lo = *reinterpret_cast<const float4*>(p);
  float4 hi = *reinterpret_cast<const float4*>(p + 4);
  float mk = ((unsigned)imgrow < (unsigned)IMG_H) ? 1.f : 0.f;  // wave-uniform
  lo.x *= mk; lo.y *= mk; lo.z *= mk; lo.w *= mk;
  hi.x *= mk; hi.y *= mk; hi.z *= mk; hi.w *= mk;
  r.lo = lo; r.hi = hi;
  float lf = __shfl_up(hi.w, 1);
  float rt = __shfl_down(lo.x, 1);
  r.lft = (lane == 0)  ? 0.f : lf;   // pixel -1  -> 0 (image edge)
  r.rgt = (lane == 63) ? 0.f : rt;   // pixel 512 -> 0
}

__global__ __launch_bounds__(256) void edgenet_kernel(
    const float* __restrict__ in, int* __restrict__ out) {
  __shared__ float lds[2][SROWS * IMG_W];               // 2 x 20 KB
  const int tid  = threadIdx.x;
  const int lane = tid & 63;
  const int w    = tid >> 6;                            // 0..3
  const int b    = blockIdx.x >> 4;                     // image index
  const int Y0   = (blockIdx.x & 15) << 5;              // block's first row
  const char* img =
      reinterpret_cast<const char*>(in + (size_t)b * (IMG_H * IMG_W));

  stage_tile(img, Y0, &lds[0][0], w, lane);             // prologue: tile 0

#pragma unroll
  for (int t = 0; t < NTILES; ++t) {
    const int y0 = Y0 + t * TROWS;
    if (t + 1 < NTILES)                                 // prefetch next tile
      stage_tile(img, y0 + TROWS, &lds[(t + 1) & 1][0], w, lane);

    // counted wait: drain stage(t) only; stage(t+1) + stores(t-1) stay live
    if (t == 0)                asm volatile("s_waitcnt vmcnt(5)" ::: "memory");
    else if (t < NTILES - 1)   asm volatile("s_waitcnt vmcnt(9)" ::: "memory");
    else                       asm volatile("s_waitcnt vmcnt(4)" ::: "memory");
    __builtin_amdgcn_sched_barrier(0);
    __builtin_amdgcn_s_barrier();                       // raw: no vmcnt(0) drain

    const float* buf = &lds[t & 1][0];
    const int r0 = w << 1;                              // wave -> 2 output rows
    Row s0, s1, s2, s3;
    ldrow(buf, r0,     y0 - 1 + r0, lane, s0);
    ldrow(buf, r0 + 1, y0     + r0, lane, s1);
    ldrow(buf, r0 + 2, y0 + 1 + r0, lane, s2);
    ldrow(buf, r0 + 3, y0 + 2 + r0, lane, s3);
    int* orow = out + ((size_t)b * IMG_H + y0 + r0) * IMG_W + (lane << 3);
    compute_store(s0, s1, s2, orow);
    compute_store(s1, s2, s3, orow + IMG_W);

    if (t + 1 < NTILES)
      __builtin_amdgcn_s_barrier();   // all ds_reads of buf[t&1] done before
                                      // iteration t+1 restages into it
  }
}

extern "C" void kernel_launch(void* const* d_in, const int* in_sizes, int n_in,
                              void* d_out, int out_size, void* d_ws, size_t ws_size,
                              hipStream_t stream) {
  const float* lab = (const float*)d_in[0];
  int* out = (int*)d_out;
  // 64 images x 16 blocks (block: 32 rows = 4 sub-tiles of 8) = 1024 blocks
  // = exactly 4 blocks/CU at 40 KB LDS -- single generation, no tail.
  int blocks = 64 * (IMG_H / (NTILES * TROWS));
  edgenet_kernel<<<blocks, 256, 0, stream>>>(lab, out);
}